// Round 1
// baseline (120.955 us; speedup 1.0000x reference)
//
#include <hip/hip_runtime.h>
#include <cstdint>
#include <cstddef>

#define Bb 128
#define Cc 64
#define Dd 365
#define Tt 364
#define Ss 32
#define SM1 31
#define NIJ 961        // 31*31
#define NIJP 964       // padded to multiple of 4
#define TTILE 16
#define BASISF 1e-10f

// ---------------------------------------------------------------------------
// Pre-kernel: pad beta to [Cc][NIJP] and mu to [NIJP] (zeros in the pad) so
// the main kernel can use aligned float4 loads (NIJ=961 is odd).
// ---------------------------------------------------------------------------
__global__ void pad_params_kernel(const float* __restrict__ mu,
                                  const float* __restrict__ beta,
                                  float* __restrict__ beta_pad,
                                  float* __restrict__ mu_pad) {
    int idx = blockIdx.x * blockDim.x + threadIdx.x;
    if (idx < Cc * NIJP) {
        int c = idx / NIJP;
        int ij = idx - c * NIJP;
        beta_pad[idx] = (ij < NIJ) ? beta[c * NIJ + ij] : 0.0f;
    }
    if (idx < NIJP) {
        mu_pad[idx] = (idx < NIJ) ? mu[idx] : 0.0f;
    }
}

// ---------------------------------------------------------------------------
// Main kernel. One block handles (b, 16 t-values). 256 threads.
//  Phase 1: stage adT[c][tt] in LDS.
//  Phase 2: register-blocked GEMM: thread owns 4 consecutive ij x 16 t.
//  Phase 3 (x2 halves of 8 t): num=exp(acc-mu) -> LDS; per-(t,i) row thread
//           computes den, Q_same = 1/den, diagonal-inserted row, stores.
// ---------------------------------------------------------------------------
template <bool PADDED>
__global__ __launch_bounds__(256, 4)
void transition_kernel(const float* __restrict__ adstock,
                       const float* __restrict__ betap,   // padded or raw
                       const float* __restrict__ mup,     // padded or raw
                       float* __restrict__ out) {
    const int b  = blockIdx.x;
    const int t0 = blockIdx.y * TTILE;
    const int tid = threadIdx.x;

    __shared__ float adT[Cc][TTILE];       // 4 KB
    __shared__ float num_lds[8][NIJP];     // 30.8 KB (8 t's at a time)

    // ---- stage adstock[b, c, 1 + t0 + tt] ----
    for (int k = tid; k < Cc * TTILE; k += 256) {
        int c  = k >> 4;
        int tt = k & 15;
        int t  = t0 + tt;
        float v = 0.0f;
        if (t < Tt) v = adstock[(size_t)b * (Cc * Dd) + c * Dd + 1 + t];
        adT[c][tt] = v;
    }
    __syncthreads();

    // ---- GEMM over c ----
    const int ij0 = tid * 4;
    const bool active = (ij0 < NIJP);   // tids 0..240

    float acc[TTILE][4];
    #pragma unroll
    for (int tt = 0; tt < TTILE; ++tt) {
        acc[tt][0] = 0.f; acc[tt][1] = 0.f; acc[tt][2] = 0.f; acc[tt][3] = 0.f;
    }

    if (active) {
        for (int c = 0; c < Cc; ++c) {
            float4 w;
            if (PADDED) {
                w = *reinterpret_cast<const float4*>(betap + (size_t)c * NIJP + ij0);
            } else {
                const float* bsrc = betap + (size_t)c * NIJ;
                w.x = (ij0 + 0 < NIJ) ? bsrc[ij0 + 0] : 0.f;
                w.y = (ij0 + 1 < NIJ) ? bsrc[ij0 + 1] : 0.f;
                w.z = (ij0 + 2 < NIJ) ? bsrc[ij0 + 2] : 0.f;
                w.w = (ij0 + 3 < NIJ) ? bsrc[ij0 + 3] : 0.f;
            }
            float4 a0 = *reinterpret_cast<const float4*>(&adT[c][0]);
            float4 a1 = *reinterpret_cast<const float4*>(&adT[c][4]);
            float4 a2 = *reinterpret_cast<const float4*>(&adT[c][8]);
            float4 a3 = *reinterpret_cast<const float4*>(&adT[c][12]);
            float av[16] = {a0.x, a0.y, a0.z, a0.w,  a1.x, a1.y, a1.z, a1.w,
                            a2.x, a2.y, a2.z, a2.w,  a3.x, a3.y, a3.z, a3.w};
            #pragma unroll
            for (int tt = 0; tt < TTILE; ++tt) {
                acc[tt][0] = fmaf(av[tt], w.x, acc[tt][0]);
                acc[tt][1] = fmaf(av[tt], w.y, acc[tt][1]);
                acc[tt][2] = fmaf(av[tt], w.z, acc[tt][2]);
                acc[tt][3] = fmaf(av[tt], w.w, acc[tt][3]);
            }
        }
    }

    // ---- mu for this thread's 4 ij ----
    float4 muv = make_float4(0.f, 0.f, 0.f, 0.f);
    if (active) {
        if (PADDED) {
            muv = *reinterpret_cast<const float4*>(mup + ij0);
        } else {
            muv.x = (ij0 + 0 < NIJ) ? mup[ij0 + 0] : 0.f;
            muv.y = (ij0 + 1 < NIJ) ? mup[ij0 + 1] : 0.f;
            muv.z = (ij0 + 2 < NIJ) ? mup[ij0 + 2] : 0.f;
            muv.w = (ij0 + 3 < NIJ) ? mup[ij0 + 3] : 0.f;
        }
    }

    const int q8   = tid >> 5;   // 0..7   (which t within the 8-half)
    const int irow = tid & 31;   // 0..31  (output row i)

    #pragma unroll
    for (int half = 0; half < 2; ++half) {
        // ---- num = exp(O_beta - mu) -> LDS for 8 t's ----
        if (active) {
            #pragma unroll
            for (int q = 0; q < 8; ++q) {
                const int tt = half * 8 + q;
                float4 n;
                n.x = __expf(acc[tt][0] - muv.x);
                n.y = __expf(acc[tt][1] - muv.y);
                n.z = __expf(acc[tt][2] - muv.z);
                n.w = __expf(acc[tt][3] - muv.w);
                *reinterpret_cast<float4*>(&num_lds[q][ij0]) = n;
            }
        }
        __syncthreads();

        // ---- per-(t, i) row epilogue ----
        {
            const int t = t0 + half * 8 + q8;
            if (t < Tt) {
                float* op = out + (((size_t)b * Tt + t) * Ss + irow) * Ss;
                if (irow < SM1) {
                    float row[SM1];
                    #pragma unroll
                    for (int j = 0; j < SM1; ++j) row[j] = num_lds[q8][irow * SM1 + j];
                    float den = 1.0f;
                    #pragma unroll
                    for (int j = 0; j < SM1; ++j) den += row[j];
                    const float inv = 1.0f / den;   // == Q_same exactly
                    #pragma unroll
                    for (int k = 0; k < 8; ++k) {
                        float o[4];
                        #pragma unroll
                        for (int u = 0; u < 4; ++u) {
                            const int j = 4 * k + u;
                            float v;
                            if (j == 0) {
                                v = (irow > 0) ? row[0] * inv : inv;
                            } else if (j == SM1) {      // j = 31, only i < 31 here
                                v = row[SM1 - 1] * inv;
                            } else {
                                v = (j < irow) ? row[j] * inv
                                               : ((j == irow) ? inv : row[j - 1] * inv);
                            }
                            o[u] = fmaxf(v, BASISF);
                        }
                        *reinterpret_cast<float4*>(op + 4 * k) =
                            make_float4(o[0], o[1], o[2], o[3]);
                    }
                } else {
                    // absorbing last row: BASIS everywhere, 1-(S-1)*BASIS at the end
                    #pragma unroll
                    for (int k = 0; k < 8; ++k) {
                        float4 o = make_float4(BASISF, BASISF, BASISF, BASISF);
                        if (k == 7) o.w = 1.0f - SM1 * BASISF;
                        *reinterpret_cast<float4*>(op + 4 * k) = o;
                    }
                }
            }
        }
        __syncthreads();  // protect num_lds before next half overwrites it
    }
}

// ---------------------------------------------------------------------------
extern "C" void kernel_launch(void* const* d_in, const int* in_sizes, int n_in,
                              void* d_out, int out_size, void* d_ws, size_t ws_size,
                              hipStream_t stream) {
    const float* adstock = (const float*)d_in[0];
    const float* mu      = (const float*)d_in[1];
    const float* beta    = (const float*)d_in[2];
    float* out = (float*)d_out;

    const size_t need = (size_t)(Cc * NIJP + NIJP) * sizeof(float);
    dim3 grid(Bb, (Tt + TTILE - 1) / TTILE);

    if (ws_size >= need) {
        float* beta_pad = (float*)d_ws;
        float* mu_pad   = beta_pad + (size_t)Cc * NIJP;
        int tot = Cc * NIJP;
        pad_params_kernel<<<(tot + 255) / 256, 256, 0, stream>>>(mu, beta, beta_pad, mu_pad);
        transition_kernel<true><<<grid, 256, 0, stream>>>(adstock, beta_pad, mu_pad, out);
    } else {
        transition_kernel<false><<<grid, 256, 0, stream>>>(adstock, beta, mu, out);
    }
}

// Round 2
// 82.661 us; speedup vs baseline: 1.4633x; 1.4633x over previous
//
#include <hip/hip_runtime.h>
#include <cstdint>
#include <cstddef>

#define Bb 128
#define Cc 64
#define Dd 365
#define Tt 364
#define Ss 32
#define SM1 31
#define NIJ 961          // 31*31
#define NPAD 1024        // padded 32*32 (n = i*32 + j)
#define BASISF 1e-10f

typedef _Float16 f16x8 __attribute__((ext_vector_type(8)));
typedef float f32x4 __attribute__((ext_vector_type(4)));

// ---------------------------------------------------------------------------
// Pre-kernel: build Bt[1024][64] f16 (transposed, padded beta) and
// mu_pad[1024] f32.  n = i*32 + j; entries with i==31 or j==31 are zero.
// ---------------------------------------------------------------------------
__global__ void prep_kernel(const float* __restrict__ mu,
                            const float* __restrict__ beta,
                            _Float16* __restrict__ Bt,
                            float* __restrict__ mu_pad) {
    int idx = blockIdx.x * blockDim.x + threadIdx.x;   // 0 .. 65535
    int n = idx >> 6;          // 0..1023
    int c = idx & 63;
    int i = n >> 5, j = n & 31;
    float v = (i < SM1 && j < SM1) ? beta[c * NIJ + i * SM1 + j] : 0.0f;
    Bt[(size_t)n * Cc + c] = (_Float16)v;
    if (idx < NPAD) {
        int ii = idx >> 5, jj = idx & 31;
        mu_pad[idx] = (ii < SM1 && jj < SM1) ? mu[ii * SM1 + jj] : 0.0f;
    }
}

// ---------------------------------------------------------------------------
// Main MFMA kernel. 512 threads = 8 waves. Block handles 32 bt-rows x 1024 n.
// Wave w: bt-half = w>>2 (16 rows), n-quarter = w&3 (256 cols = 8 i-rows).
// GEMM: O[bt][n] = sum_c A[bt][c] * Bt[n][c], f16 in / f32 out.
// Epilogue fully in-register: exp, 16-lane shfl reduce for den,
// diagonal-insert via shfl, coalesced dword stores.
// ---------------------------------------------------------------------------
__global__ __launch_bounds__(512, 4)
void transition_mfma_kernel(const float* __restrict__ adstock,
                            const _Float16* __restrict__ Bt,
                            const float* __restrict__ mu_pad,
                            float* __restrict__ out) {
    const int bt0 = blockIdx.x * 32;
    const int tid = threadIdx.x;
    const int lane = tid & 63;
    const int w = tid >> 6;            // 0..7
    const int je = lane & 15;          // 0..15
    const int grp = lane >> 4;         // 0..3
    const int mh = w >> 2;             // bt half (0/1)
    const int n0 = (w & 3) * 256;      // n-quarter base

    __shared__ __align__(16) _Float16 Alds[32][80];   // 5 KB, padded rows

    // ---- stage A tile: adstock[b][c][1+t] -> Alds[m][c] (f16) ----
    for (int e = tid; e < 32 * Cc; e += 512) {
        int c = e >> 5;                 // 0..63
        int m = e & 31;                 // 0..31
        int bt = bt0 + m;
        int b = bt / Tt;
        int t = bt - b * Tt;
        float v = adstock[(size_t)b * (Cc * Dd) + c * Dd + 1 + t];
        Alds[m][c] = (_Float16)v;
    }
    __syncthreads();

    // ---- GEMM: 2 k-steps of 32, 16 n-frags ----
    f32x4 acc[16];
    #pragma unroll
    for (int f = 0; f < 16; ++f) acc[f] = (f32x4){0.f, 0.f, 0.f, 0.f};

    #pragma unroll
    for (int ks = 0; ks < 2; ++ks) {
        const int kbase = ks * 32 + grp * 8;
        // A-frag: row = je (within this wave's 16-row half), k = kbase..+7
        f16x8 afrag = *reinterpret_cast<const f16x8*>(&Alds[mh * 16 + je][kbase]);
        #pragma unroll
        for (int f = 0; f < 16; ++f) {
            const int col = n0 + f * 16 + je;
            f16x8 bfrag = *reinterpret_cast<const f16x8*>(Bt + (size_t)col * Cc + kbase);
            acc[f] = __builtin_amdgcn_mfma_f32_16x16x32_f16(afrag, bfrag, acc[f], 0, 0, 0);
        }
    }

    // ---- epilogue: 8 i-rows per wave, fully in-register ----
    const size_t outbase = ((size_t)bt0 + mh * 16) * NPAD;
    const int src = (lane & 48) | ((je - 1) & 15);   // lane je-1 within group (wraps to 15)

    #pragma unroll
    for (int q = 0; q < 8; ++q) {
        const int i = (w & 3) * 8 + q;               // output row index 0..31
        const float mu_e = mu_pad[i * 32 + je];
        const float mu_o = mu_pad[i * 32 + 16 + je];
        f32x4 fe = acc[2 * q];
        f32x4 fo = acc[2 * q + 1];

        float ne[4], no[4], s[4];
        #pragma unroll
        for (int r = 0; r < 4; ++r) {
            ne[r] = __expf(fe[r] - mu_e);            // num[j = je]
            no[r] = __expf(fo[r] - mu_o);            // num[j = 16+je]
            s[r] = ne[r] + ((je == 15) ? 0.f : no[r]);  // mask padded j=31
        }
        // 16-lane group sum -> den partial in every lane
        #pragma unroll
        for (int d = 1; d < 16; d <<= 1) {
            #pragma unroll
            for (int r = 0; r < 4; ++r) s[r] += __shfl_xor(s[r], d);
        }

        #pragma unroll
        for (int r = 0; r < 4; ++r) {
            const float inv = 1.0f / (1.0f + s[r]);          // == Q_same exactly
            const float sh_e = __shfl(ne[r], src);           // num[je-1]
            const float sh_o = __shfl((je == 15) ? ne[r] : no[r], src); // num[15+je]
            float ve, vo;
            if (i == SM1) {
                // absorbing last row: BASIS everywhere, 1-(S-1)*BASIS at col 31
                ve = BASISF;
                vo = (je == 15) ? (1.0f - SM1 * BASISF) : BASISF;
            } else {
                const int jo2 = 16 + je;
                ve = (je  < i) ? ne[r] * inv : ((je  == i) ? inv : sh_e * inv);
                vo = (jo2 < i) ? no[r] * inv : ((jo2 == i) ? inv : sh_o * inv);
                ve = fmaxf(ve, BASISF);
                vo = fmaxf(vo, BASISF);
            }
            float* op = out + outbase + (size_t)(grp * 4 + r) * NPAD + i * 32;
            op[je] = ve;
            op[16 + je] = vo;
        }
    }
}

// ---------------------------------------------------------------------------
// Fallback (no workspace): round-1 scalar kernel, unpadded loads.
// ---------------------------------------------------------------------------
__global__ __launch_bounds__(256, 4)
void transition_fallback_kernel(const float* __restrict__ adstock,
                                const float* __restrict__ beta,
                                const float* __restrict__ mu,
                                float* __restrict__ out) {
    const int b  = blockIdx.x;
    const int t0 = blockIdx.y * 16;
    const int tid = threadIdx.x;

    __shared__ float adT[Cc][16];
    __shared__ float num_lds[8][964];

    for (int k = tid; k < Cc * 16; k += 256) {
        int c = k >> 4, tt = k & 15, t = t0 + tt;
        adT[c][tt] = (t < Tt) ? adstock[(size_t)b * (Cc * Dd) + c * Dd + 1 + t] : 0.0f;
    }
    __syncthreads();

    const int ij0 = tid * 4;
    const bool active = (ij0 < 964);
    float acc[16][4];
    #pragma unroll
    for (int tt = 0; tt < 16; ++tt) { acc[tt][0]=0;acc[tt][1]=0;acc[tt][2]=0;acc[tt][3]=0; }

    if (active) {
        for (int c = 0; c < Cc; ++c) {
            const float* bsrc = beta + (size_t)c * NIJ;
            float w0 = (ij0+0<NIJ)?bsrc[ij0+0]:0.f, w1 = (ij0+1<NIJ)?bsrc[ij0+1]:0.f;
            float w2 = (ij0+2<NIJ)?bsrc[ij0+2]:0.f, w3 = (ij0+3<NIJ)?bsrc[ij0+3]:0.f;
            #pragma unroll
            for (int tt = 0; tt < 16; ++tt) {
                float a = adT[c][tt];
                acc[tt][0] = fmaf(a, w0, acc[tt][0]);
                acc[tt][1] = fmaf(a, w1, acc[tt][1]);
                acc[tt][2] = fmaf(a, w2, acc[tt][2]);
                acc[tt][3] = fmaf(a, w3, acc[tt][3]);
            }
        }
    }
    float m0=0,m1=0,m2=0,m3=0;
    if (active) {
        m0 = (ij0+0<NIJ)?mu[ij0+0]:0.f; m1 = (ij0+1<NIJ)?mu[ij0+1]:0.f;
        m2 = (ij0+2<NIJ)?mu[ij0+2]:0.f; m3 = (ij0+3<NIJ)?mu[ij0+3]:0.f;
    }
    const int q8 = tid >> 5, irow = tid & 31;
    #pragma unroll
    for (int half = 0; half < 2; ++half) {
        if (active) {
            #pragma unroll
            for (int q = 0; q < 8; ++q) {
                const int tt = half * 8 + q;
                num_lds[q][ij0+0] = __expf(acc[tt][0] - m0);
                num_lds[q][ij0+1] = __expf(acc[tt][1] - m1);
                num_lds[q][ij0+2] = __expf(acc[tt][2] - m2);
                num_lds[q][ij0+3] = __expf(acc[tt][3] - m3);
            }
        }
        __syncthreads();
        const int t = t0 + half * 8 + q8;
        if (t < Tt) {
            float* op = out + (((size_t)b * Tt + t) * Ss + irow) * Ss;
            if (irow < SM1) {
                float row[SM1]; float den = 1.0f;
                #pragma unroll
                for (int j = 0; j < SM1; ++j) { row[j] = num_lds[q8][irow*SM1+j]; den += row[j]; }
                const float inv = 1.0f / den;
                #pragma unroll
                for (int j = 0; j < Ss; ++j) {
                    float v = (j < irow) ? row[j]*inv : ((j == irow) ? inv
                              : (j-1 < SM1 ? row[j-1]*inv : 0.f));
                    op[j] = fmaxf(v, BASISF);
                }
            } else {
                #pragma unroll
                for (int j = 0; j < Ss; ++j) op[j] = (j == SM1) ? (1.0f - SM1*BASISF) : BASISF;
            }
        }
        __syncthreads();
    }
}

// ---------------------------------------------------------------------------
extern "C" void kernel_launch(void* const* d_in, const int* in_sizes, int n_in,
                              void* d_out, int out_size, void* d_ws, size_t ws_size,
                              hipStream_t stream) {
    const float* adstock = (const float*)d_in[0];
    const float* mu      = (const float*)d_in[1];
    const float* beta    = (const float*)d_in[2];
    float* out = (float*)d_out;

    const size_t need = (size_t)NPAD * Cc * sizeof(_Float16) + NPAD * sizeof(float);

    if (ws_size >= need) {
        _Float16* Bt = (_Float16*)d_ws;
        float* mu_pad = (float*)((char*)d_ws + (size_t)NPAD * Cc * sizeof(_Float16));
        prep_kernel<<<(NPAD * Cc) / 256, 256, 0, stream>>>(mu, beta, Bt, mu_pad);
        const int nblocks = (Bb * Tt) / 32;   // 46592/32 = 1456 exact
        transition_mfma_kernel<<<nblocks, 512, 0, stream>>>(adstock, Bt, mu_pad, out);
    } else {
        dim3 grid(Bb, (Tt + 15) / 16);
        transition_fallback_kernel<<<grid, 256, 0, stream>>>(adstock, beta, mu, out);
    }
}

// Round 3
// 64.416 us; speedup vs baseline: 1.8777x; 1.2832x over previous
//
#include <hip/hip_runtime.h>
#include <cstdint>
#include <cstddef>

#define Bb 128
#define Cc 64
#define Dd 365
#define Tt 364
#define Ss 32
#define SM1 31
#define NIJ 961
#define BASISF 1e-10f

typedef _Float16 f16x8 __attribute__((ext_vector_type(8)));
typedef float f32x4 __attribute__((ext_vector_type(4)));

// ---------------------------------------------------------------------------
// Prep: permuted+padded Bt[1024][64] f16 and mu_perm[1024] f32.
// MFMA column index m <-> (i, j):  i = m>>5, v = m&31, p = v>>4, je = v&15,
// j = 2*je + p.  (Even/odd j interleave so frag pairs give each lane adjacent
// j's -> dwordx2 stores and a lane-local diagonal shift for odd j.)
// ---------------------------------------------------------------------------
__global__ void prep_kernel(const float* __restrict__ mu,
                            const float* __restrict__ beta,
                            _Float16* __restrict__ Bt,
                            float* __restrict__ mu_perm) {
    int idx = blockIdx.x * blockDim.x + threadIdx.x;   // 0 .. 65535
    int m = idx >> 6, c = idx & 63;
    int i = m >> 5, v = m & 31, p = v >> 4, je = v & 15, j = 2 * je + p;
    float val = (i < SM1 && j < SM1) ? beta[c * NIJ + i * SM1 + j] : 0.0f;
    Bt[(size_t)m * Cc + c] = (_Float16)val;
    if (idx < 1024) {
        int ii = idx >> 5, vv = idx & 31, pp = vv >> 4, jj = 2 * (vv & 15) + pp;
        mu_perm[idx] = (ii < SM1 && jj < SM1) ? mu[ii * SM1 + jj] : 0.0f;
    }
}

// ---- DPP helpers (row ops act within each 16-lane row; all VALU, no DS) ----
template <int CTRL>
__device__ __forceinline__ float dpp_add(float s) {
    union { float f; int i; } u, v;
    u.f = s;
    v.i = __builtin_amdgcn_update_dpp(0, u.i, CTRL, 0xf, 0xf, true);
    return s + v.f;
}
__device__ __forceinline__ float dpp_shr1(float x) {   // lane i <- lane i-1
    union { float f; int i; } u, v;
    u.f = x;
    v.i = __builtin_amdgcn_update_dpp(0, u.i, 0x111, 0xf, 0xf, true);
    return v.f;
}

// ---------------------------------------------------------------------------
// Main kernel: 512 threads = 8 waves; block = 32 bt-rows x 1024 m-cols.
// Wave w: bt-half mh = w>>2, m-quarter nq = w&3 (8 output i-rows).
// Per q (one i-row): prefetch next B frags, 4 MFMAs into 2 live frags,
// epilogue fully in-register with DPP reduce + fast rcp + dwordx2 stores.
// ---------------------------------------------------------------------------
__global__ __launch_bounds__(512, 4)
void transition_mfma_kernel(const float* __restrict__ adstock,
                            const _Float16* __restrict__ Bt,
                            const float* __restrict__ mu_perm,
                            float* __restrict__ out)
{
    const int bt0 = blockIdx.x * 32;
    const int tid = threadIdx.x;
    const int lane = tid & 63;
    const int w   = tid >> 6;
    const int je  = lane & 15;
    const int grp = lane >> 4;
    const int mh  = w >> 2;
    const int nq  = w & 3;

    __shared__ __align__(16) _Float16 Alds[32][72];   // 4.5 KB
    __shared__ float muL[1024];                       // 4 KB

    // ---- stage A tile (f32 -> f16) and mu ----
    for (int e = tid; e < 32 * Cc; e += 512) {
        int c = e >> 5, m = e & 31;
        int bt = bt0 + m, b = bt / Tt, t = bt - b * Tt;
        Alds[m][c] = (_Float16)adstock[((size_t)b * Cc + c) * Dd + 1 + t];
    }
    for (int e = tid; e < 1024; e += 512) muL[e] = mu_perm[e];
    __syncthreads();

    const int arow = mh * 16 + je;
    const f16x8 a0 = *reinterpret_cast<const f16x8*>(&Alds[arow][grp * 8]);
    const f16x8 a1 = *reinterpret_cast<const f16x8*>(&Alds[arow][32 + grp * 8]);

    // lane base into Bt; frag(f,ks) at bp + f*16*64 + ks*32
    const _Float16* bp = Bt + ((size_t)(nq * 256 + je)) * Cc + grp * 8;

    f16x8 b00 = *reinterpret_cast<const f16x8*>(bp + 0);
    f16x8 b01 = *reinterpret_cast<const f16x8*>(bp + 32);
    f16x8 b10 = *reinterpret_cast<const f16x8*>(bp + 1024);
    f16x8 b11 = *reinterpret_cast<const f16x8*>(bp + 1024 + 32);

    const float omask = (je == 15) ? 0.0f : 1.0f;   // mask padded j=31 in den

    float* outp[4];
    #pragma unroll
    for (int r = 0; r < 4; ++r)
        outp[r] = out + ((size_t)(bt0 + mh * 16 + grp * 4 + r)) * 1024
                      + nq * 256 + je * 2;
    // store for (q, r): outp[r] + q*32   (i = nq*8 + q; i*32 = nq*256 + q*32)

    #pragma unroll
    for (int q = 0; q < 8; ++q) {
        // ---- prefetch next q's B frags ----
        f16x8 n00, n01, n10, n11;
        if (q < 7) {
            const _Float16* np = bp + (q + 1) * 2048;
            n00 = *reinterpret_cast<const f16x8*>(np + 0);
            n01 = *reinterpret_cast<const f16x8*>(np + 32);
            n10 = *reinterpret_cast<const f16x8*>(np + 1024);
            n11 = *reinterpret_cast<const f16x8*>(np + 1024 + 32);
        }

        f32x4 acc0 = {0.f, 0.f, 0.f, 0.f}, acc1 = {0.f, 0.f, 0.f, 0.f};
        acc0 = __builtin_amdgcn_mfma_f32_16x16x32_f16(a0, b00, acc0, 0, 0, 0);
        acc0 = __builtin_amdgcn_mfma_f32_16x16x32_f16(a1, b01, acc0, 0, 0, 0);
        acc1 = __builtin_amdgcn_mfma_f32_16x16x32_f16(a0, b10, acc1, 0, 0, 0);
        acc1 = __builtin_amdgcn_mfma_f32_16x16x32_f16(a1, b11, acc1, 0, 0, 0);

        const int i = nq * 8 + q;                    // output row (wave-uniform)
        const float mu_e = muL[i * 32 + je];         // broadcast reads
        const float mu_o = muL[i * 32 + 16 + je];

        if (i == SM1) {
            // absorbing last row: BASIS everywhere, 1-(S-1)*BASIS at col 31
            float2 vv;
            vv.x = BASISF;
            vv.y = (je == 15) ? (1.0f - SM1 * BASISF) : BASISF;
            #pragma unroll
            for (int r = 0; r < 4; ++r)
                *reinterpret_cast<float2*>(outp[r] + q * 32) = vv;
        } else {
            const int j_e = 2 * je, j_o = 2 * je + 1;
            #pragma unroll
            for (int r = 0; r < 4; ++r) {
                float ne = __expf(acc0[r] - mu_e);   // num[j = 2*je]
                float no = __expf(acc1[r] - mu_o);   // num[j = 2*je+1]
                float s = fmaf(no, omask, ne);
                s = dpp_add<0x128>(s);               // row_ror:8
                s = dpp_add<0x124>(s);               // row_ror:4
                s = dpp_add<0x122>(s);               // row_ror:2
                s = dpp_add<0x121>(s);               // row_ror:1
                const float inv = __builtin_amdgcn_rcpf(1.0f + s);  // Q_same
                const float she = dpp_shr1(no);      // num[2*je - 1]
                const float pe = ne * inv, po = no * inv, pse = she * inv;
                float ve = (j_e < i) ? pe : ((j_e == i) ? inv : pse);
                float vo = (j_o < i) ? po : ((j_o == i) ? inv : pe);
                float2 vv;
                vv.x = fmaxf(ve, BASISF);
                vv.y = fmaxf(vo, BASISF);
                *reinterpret_cast<float2*>(outp[r] + q * 32) = vv;
            }
        }
        b00 = n00; b01 = n01; b10 = n10; b11 = n11;
    }
}

// ---------------------------------------------------------------------------
// Fallback (no workspace): round-1 scalar kernel.
// ---------------------------------------------------------------------------
__global__ __launch_bounds__(256, 4)
void transition_fallback_kernel(const float* __restrict__ adstock,
                                const float* __restrict__ beta,
                                const float* __restrict__ mu,
                                float* __restrict__ out) {
    const int b  = blockIdx.x;
    const int t0 = blockIdx.y * 16;
    const int tid = threadIdx.x;

    __shared__ float adT[Cc][16];
    __shared__ float num_lds[8][964];

    for (int k = tid; k < Cc * 16; k += 256) {
        int c = k >> 4, tt = k & 15, t = t0 + tt;
        adT[c][tt] = (t < Tt) ? adstock[(size_t)b * (Cc * Dd) + c * Dd + 1 + t] : 0.0f;
    }
    __syncthreads();

    const int ij0 = tid * 4;
    const bool active = (ij0 < 964);
    float acc[16][4];
    #pragma unroll
    for (int tt = 0; tt < 16; ++tt) { acc[tt][0]=0;acc[tt][1]=0;acc[tt][2]=0;acc[tt][3]=0; }

    if (active) {
        for (int c = 0; c < Cc; ++c) {
            const float* bsrc = beta + (size_t)c * NIJ;
            float w0 = (ij0+0<NIJ)?bsrc[ij0+0]:0.f, w1 = (ij0+1<NIJ)?bsrc[ij0+1]:0.f;
            float w2 = (ij0+2<NIJ)?bsrc[ij0+2]:0.f, w3 = (ij0+3<NIJ)?bsrc[ij0+3]:0.f;
            #pragma unroll
            for (int tt = 0; tt < 16; ++tt) {
                float a = adT[c][tt];
                acc[tt][0] = fmaf(a, w0, acc[tt][0]);
                acc[tt][1] = fmaf(a, w1, acc[tt][1]);
                acc[tt][2] = fmaf(a, w2, acc[tt][2]);
                acc[tt][3] = fmaf(a, w3, acc[tt][3]);
            }
        }
    }
    float m0=0,m1=0,m2=0,m3=0;
    if (active) {
        m0 = (ij0+0<NIJ)?mu[ij0+0]:0.f; m1 = (ij0+1<NIJ)?mu[ij0+1]:0.f;
        m2 = (ij0+2<NIJ)?mu[ij0+2]:0.f; m3 = (ij0+3<NIJ)?mu[ij0+3]:0.f;
    }
    const int q8 = tid >> 5, irow = tid & 31;
    #pragma unroll
    for (int half = 0; half < 2; ++half) {
        if (active) {
            #pragma unroll
            for (int q = 0; q < 8; ++q) {
                const int tt = half * 8 + q;
                num_lds[q][ij0+0] = __expf(acc[tt][0] - m0);
                num_lds[q][ij0+1] = __expf(acc[tt][1] - m1);
                num_lds[q][ij0+2] = __expf(acc[tt][2] - m2);
                num_lds[q][ij0+3] = __expf(acc[tt][3] - m3);
            }
        }
        __syncthreads();
        const int t = t0 + half * 8 + q8;
        if (t < Tt) {
            float* op = out + (((size_t)b * Tt + t) * Ss + irow) * Ss;
            if (irow < SM1) {
                float row[SM1]; float den = 1.0f;
                #pragma unroll
                for (int j = 0; j < SM1; ++j) { row[j] = num_lds[q8][irow*SM1+j]; den += row[j]; }
                const float inv = 1.0f / den;
                #pragma unroll
                for (int j = 0; j < Ss; ++j) {
                    float v = (j < irow) ? row[j]*inv : ((j == irow) ? inv
                              : (j-1 < SM1 ? row[j-1]*inv : 0.f));
                    op[j] = fmaxf(v, BASISF);
                }
            } else {
                #pragma unroll
                for (int j = 0; j < Ss; ++j) op[j] = (j == SM1) ? (1.0f - SM1*BASISF) : BASISF;
            }
        }
        __syncthreads();
    }
}

// ---------------------------------------------------------------------------
extern "C" void kernel_launch(void* const* d_in, const int* in_sizes, int n_in,
                              void* d_out, int out_size, void* d_ws, size_t ws_size,
                              hipStream_t stream) {
    const float* adstock = (const float*)d_in[0];
    const float* mu      = (const float*)d_in[1];
    const float* beta    = (const float*)d_in[2];
    float* out = (float*)d_out;

    const size_t need = (size_t)1024 * Cc * sizeof(_Float16) + 1024 * sizeof(float);

    if (ws_size >= need) {
        _Float16* Bt = (_Float16*)d_ws;
        float* mu_perm = (float*)((char*)d_ws + (size_t)1024 * Cc * sizeof(_Float16));
        prep_kernel<<<(1024 * Cc) / 256, 256, 0, stream>>>(mu, beta, Bt, mu_perm);
        const int nblocks = (Bb * Tt) / 32;   // 1456
        transition_mfma_kernel<<<nblocks, 512, 0, stream>>>(adstock, Bt, mu_perm, out);
    } else {
        dim3 grid(Bb, (Tt + 15) / 16);
        transition_fallback_kernel<<<grid, 256, 0, stream>>>(adstock, beta, mu, out);
    }
}